// Round 9
// baseline (2913.786 us; speedup 1.0000x reference)
//
#include <hip/hip_runtime.h>
#include <math.h>

#define S_LEN 256
#define NCELL 8
#define HID 16
#define MEM 20
#define NB 4
#define NTHR 1024
#define KS 16

typedef _Float16 h2 __attribute__((ext_vector_type(2)));

#if defined(__has_builtin)
#if __has_builtin(__builtin_amdgcn_fdot2)
#define HAVE_FDOT2 1
#endif
#endif

__device__ __forceinline__ float sigm(float v) { return 1.0f / (1.0f + __expf(-v)); }
__device__ __forceinline__ float tanh_f(float v) { return 1.0f - 2.0f / (__expf(2.0f * v) + 1.0f); }
__device__ __forceinline__ float dot4(float4 a, float4 b) {
    return fmaf(a.x, b.x, fmaf(a.y, b.y, fmaf(a.z, b.z, a.w * b.w)));
}
__device__ __forceinline__ h2 bch2(float f) { return __builtin_bit_cast(h2, f); }
__device__ __forceinline__ float dot2acc(h2 a, h2 w, float c) {
#ifdef HAVE_FDOT2
    return __builtin_amdgcn_fdot2(a, w, c, false);
#else
    return fmaf((float)a.x, (float)w.x, fmaf((float)a.y, (float)w.y, c));
#endif
}

// W1 f32 [64][2580] -> W1F f16 [m][ks][j][8] (h-cols only), coalesced reads.
__global__ __launch_bounds__(256)
void prep_w1(const float* __restrict__ W1, _Float16* __restrict__ W1F) {
    int d = blockIdx.x * 256 + threadIdx.x;
    if (d < MEM * KS * 64 * 8) {
        int e = d & 7, j = (d >> 3) & 63, ks = (d >> 9) & 15, m = d >> 13;
        W1F[d] = (_Float16)W1[j * 2580 + m * 129 + ks * 8 + e];
    }
}

// R8 post-mortem: VALUBusy 22% -- serial phase chain (stream stalls -> 4-wave
// reduce -> 1-wave tail) leaves SIMDs idle. R9: one-step pipeline. partial(t+1)
// = sum_{m>=1} W1_m . row_{t+1-m} is computable during step t (rows known after
// phase A). Waves 8-15 stream W1F m=1..19 for NEXT step while waves 0-3
// assemble e1(t) (prev partial + LDS-resident W1_0 . row_t + err col) and
// wave 0 runs the tail. red[] is parity-double-buffered; 3 barriers/step.
__global__ __attribute__((amdgpu_flat_work_group_size(NTHR, NTHR)))
void mmoe_kernel(const float* __restrict__ x, const float* __restrict__ pred0,
                 const float* __restrict__ gate0,
                 const float* __restrict__ W_ih, const float* __restrict__ W_hh,
                 const float* __restrict__ b_ih, const float* __restrict__ b_hh,
                 const float* __restrict__ W_o, const float* __restrict__ b_o,
                 const float* __restrict__ W1, const float* __restrict__ b1,
                 const float* __restrict__ W2, const float* __restrict__ b2,
                 const float* __restrict__ Wg, const float* __restrict__ bg,
                 const float* __restrict__ Wa_ih, const float* __restrict__ Wa_hh,
                 const float* __restrict__ ba_ih, const float* __restrict__ ba_hh,
                 const _Float16* __restrict__ W1F,
                 float* __restrict__ out)
{
    __shared__ __align__(16) _Float16 ringH[NB][MEM][128];   // memory rows (h), f16
    __shared__ float errS[NB][MEM];                          // error column, f32
    __shared__ __align__(16) float Whh_l[512 * 20];
    __shared__ float Wih_l[512], bias_l[512];
    __shared__ __align__(16) float WaI[2][64 * 20], WaH[2][64 * 20];
    __shared__ float ba_l[2][64];
    __shared__ __align__(16) float W2_l[16 * 68];
    __shared__ float b2_l[16];
    __shared__ __align__(16) float Wg_l[8][16], Wo_l[8][16];
    __shared__ float bg_l[8], bo_l[8];
    __shared__ float Werr_l[MEM * 64];                       // W1 col-128, f32
    __shared__ float b1_l[64];
    __shared__ __align__(16) _Float16 W10_l[64][136];        // W1 m=0 h-block, f16
    __shared__ float xS[NB][S_LEN];
    __shared__ __align__(16) float ehS[NB][HID], ecS[NB][HID];
    __shared__ __align__(16) float nhS[NB][NCELL][HID], ncS[NB][NCELL][HID];
    __shared__ float oS[NB][NCELL], predS[NB], gateS[NB][NCELL];
    __shared__ __align__(16) float ahS[2][NB][HID], acS[2][NB][HID];
    __shared__ __align__(16) float e1S[NB][64], aiS[NB][HID];
    __shared__ __align__(16) float glog[NB][8];
    __shared__ float red[2][8][64][5];                       // [parity][sg][j][b], pad 5

    const int tid = threadIdx.x;
    const int b0 = blockIdx.x * NB;

    // ---- one-time staging ----
    for (int i = tid; i < 512 * 16; i += NTHR) { int g = i >> 4, q = i & 15; Whh_l[g * 20 + q] = W_hh[i]; }
    for (int i = tid; i < 512; i += NTHR) { Wih_l[i] = W_ih[i]; bias_l[i] = b_ih[i] + b_hh[i]; }
    for (int i = tid; i < 2048; i += NTHR) {
        int l = i >> 10, r = i & 1023, g = r >> 4, q = r & 15;
        WaI[l][g * 20 + q] = Wa_ih[i]; WaH[l][g * 20 + q] = Wa_hh[i];
    }
    for (int i = tid; i < 128; i += NTHR) { int l = i >> 6, g = i & 63; ba_l[l][g] = ba_ih[i] + ba_hh[i]; }
    for (int i = tid; i < 1024; i += NTHR) { int r = i >> 6, q = i & 63; W2_l[r * 68 + q] = W2[i]; }
    for (int i = tid; i < 1280; i += NTHR) { int m = i >> 6, j = i & 63; Werr_l[i] = W1[j * 2580 + m * 129 + 128]; }
    for (int i = tid; i < 64 * 128; i += NTHR) { int j = i >> 7, k = i & 127; W10_l[j][k] = (_Float16)W1[j * 2580 + k]; }
    if (tid < 64) b1_l[tid] = b1[tid];
    if (tid < 16) b2_l[tid] = b2[tid];
    if (tid < 128) { int c = tid >> 4, h = tid & 15; Wg_l[c][h] = Wg[tid]; Wo_l[c][h] = W_o[tid]; }
    if (tid < 8) { bg_l[tid] = bg[tid]; bo_l[tid] = b_o[tid]; }
    for (int i = tid; i < NB * S_LEN; i += NTHR) { int b = i >> 8, s = i & 255; xS[b][s] = x[(b0 + b) * S_LEN + s]; }
    for (int i = tid; i < NB * MEM * 128; i += NTHR) ((_Float16*)ringH)[i] = (_Float16)0.0f;
    for (int i = tid; i < 2 * 8 * 64 * 5; i += NTHR) ((float*)red)[i] = 0.0f;   // partial(t=0)=0 (mem h=0)
    if (tid < NB * MEM) { int b = tid / MEM, m = tid % MEM; errS[b][m] = 0.5f; }
    if (tid < NB * HID) {
        int b = tid >> 4, h = tid & 15;
        ehS[b][h] = 0.f; ecS[b][h] = 0.f;
        ahS[0][b][h] = 0.f; ahS[1][b][h] = 0.f;
        acS[0][b][h] = 0.f; acS[1][b][h] = 0.f;
    }
    if (tid < NB) predS[tid] = pred0[b0 + tid];
    if (tid < NB * NCELL) { int b = tid >> 3, c = tid & 7; gateS[b][c] = gate0[(b0 + b) * NCELL + c]; }
    __syncthreads();

    const int sj = tid & 63, sg = (tid >> 6) & 7;            // stream identity (tid>=512)
    const float4* W1F4 = (const float4*)W1F;

// per-m stream compute: term m of partial(t+1) uses row slot (head+m-1)%MEM
#define SLOAD(MM, A, B) { A = W1F4[((MM) * 16 + 2 * sg) * 64 + sj]; \
                          B = W1F4[((MM) * 16 + 2 * sg + 1) * 64 + sj]; }
#define SCOMP(MM, WA, WB) { \
    int sl = head + (MM) - 1; if (sl >= MEM) sl -= MEM; \
    h2 w0 = bch2(WA.x), w1 = bch2(WA.y), w2 = bch2(WA.z), w3 = bch2(WA.w); \
    h2 w4 = bch2(WB.x), w5 = bch2(WB.y), w6 = bch2(WB.z), w7 = bch2(WB.w); \
    { float4 aA = *(const float4*)&ringH[0][sl][sg * 16]; \
      float4 aB = *(const float4*)&ringH[0][sl][sg * 16 + 8]; \
      sa0 = dot2acc(bch2(aA.x), w0, sa0); sa0 = dot2acc(bch2(aA.y), w1, sa0); \
      sa0 = dot2acc(bch2(aA.z), w2, sa0); sa0 = dot2acc(bch2(aA.w), w3, sa0); \
      sa0 = dot2acc(bch2(aB.x), w4, sa0); sa0 = dot2acc(bch2(aB.y), w5, sa0); \
      sa0 = dot2acc(bch2(aB.z), w6, sa0); sa0 = dot2acc(bch2(aB.w), w7, sa0); } \
    { float4 aA = *(const float4*)&ringH[1][sl][sg * 16]; \
      float4 aB = *(const float4*)&ringH[1][sl][sg * 16 + 8]; \
      sa1 = dot2acc(bch2(aA.x), w0, sa1); sa1 = dot2acc(bch2(aA.y), w1, sa1); \
      sa1 = dot2acc(bch2(aA.z), w2, sa1); sa1 = dot2acc(bch2(aA.w), w3, sa1); \
      sa1 = dot2acc(bch2(aB.x), w4, sa1); sa1 = dot2acc(bch2(aB.y), w5, sa1); \
      sa1 = dot2acc(bch2(aB.z), w6, sa1); sa1 = dot2acc(bch2(aB.w), w7, sa1); } \
    { float4 aA = *(const float4*)&ringH[2][sl][sg * 16]; \
      float4 aB = *(const float4*)&ringH[2][sl][sg * 16 + 8]; \
      sa2 = dot2acc(bch2(aA.x), w0, sa2); sa2 = dot2acc(bch2(aA.y), w1, sa2); \
      sa2 = dot2acc(bch2(aA.z), w2, sa2); sa2 = dot2acc(bch2(aA.w), w3, sa2); \
      sa2 = dot2acc(bch2(aB.x), w4, sa2); sa2 = dot2acc(bch2(aB.y), w5, sa2); \
      sa2 = dot2acc(bch2(aB.z), w6, sa2); sa2 = dot2acc(bch2(aB.w), w7, sa2); } \
    { float4 aA = *(const float4*)&ringH[3][sl][sg * 16]; \
      float4 aB = *(const float4*)&ringH[3][sl][sg * 16 + 8]; \
      sa3 = dot2acc(bch2(aA.x), w0, sa3); sa3 = dot2acc(bch2(aA.y), w1, sa3); \
      sa3 = dot2acc(bch2(aA.z), w2, sa3); sa3 = dot2acc(bch2(aA.w), w3, sa3); \
      sa3 = dot2acc(bch2(aB.x), w4, sa3); sa3 = dot2acc(bch2(aB.y), w5, sa3); \
      sa3 = dot2acc(bch2(aB.z), w6, sa3); sa3 = dot2acc(bch2(aB.w), w7, sa3); } }

    int head = 0;
    #pragma unroll 1
    for (int t = 0; t < S_LEN; ++t) {
        head = (head == 0) ? (MEM - 1) : (head - 1);
        const int par = t & 1;
        float sa0 = 0.f, sa1 = 0.f, sa2 = 0.f, sa3 = 0.f;    // stream accs (waves 8-15)

        // ---- Phase A (tid<512): 8 expert LSTM cells, 4 batch ----
        if (tid < 512) {
            int b = tid >> 7, c = (tid >> 4) & 7, h = tid & 15;
            float xv = xS[b][t];
            const float4* ep = (const float4*)&ehS[b][0];
            float4 e0 = ep[0], e1v = ep[1], e2 = ep[2], e3 = ep[3];
            float zg[4];
            #pragma unroll
            for (int gi = 0; gi < 4; ++gi) {
                int g = c * 64 + gi * 16 + h;
                const float* wr = &Whh_l[g * 20];
                float z = bias_l[g] + xv * Wih_l[g];
                z += dot4(e0, *(const float4*)&wr[0]) + dot4(e1v, *(const float4*)&wr[4])
                   + dot4(e2, *(const float4*)&wr[8]) + dot4(e3, *(const float4*)&wr[12]);
                zg[gi] = z;
            }
            float cc = ecS[b][h];
            float c2 = sigm(zg[1]) * cc + sigm(zg[0]) * tanh_f(zg[2]);
            float hv = sigm(zg[3]) * tanh_f(c2);
            nhS[b][c][h] = hv; ncS[b][c][h] = c2;
            ringH[b][head][c * 16 + h] = (_Float16)hv;
            if (tid < NB) errS[tid][head] = xS[tid][t] - predS[tid];
        }
        __syncthreads();   // B1

        // ---- concurrent pre-section ----
        if (tid < 256) {
            // e1(t) assembly: prev partial + W1_0 . row_t + err col + bias + relu
            int bb = tid >> 6, j = tid & 63;
            float v = b1_l[j];
            #pragma unroll
            for (int g = 0; g < 8; ++g) v += red[par][g][j][bb];
            const float4* wrow = (const float4*)&W10_l[j][0];
            const float4* arow = (const float4*)&ringH[bb][head][0];
            #pragma unroll
            for (int k4 = 0; k4 < 16; ++k4) {
                float4 w = wrow[k4];
                float4 a = arow[k4];
                v = dot2acc(bch2(a.x), bch2(w.x), v);
                v = dot2acc(bch2(a.y), bch2(w.y), v);
                v = dot2acc(bch2(a.z), bch2(w.z), v);
                v = dot2acc(bch2(a.w), bch2(w.w), v);
            }
            #pragma unroll
            for (int m = 0; m < MEM; ++m) {
                int sl = head + m; if (sl >= MEM) sl -= MEM;
                v = fmaf(Werr_l[m * 64 + j], errS[bb][sl], v);
            }
            e1S[bb][j] = fmaxf(v, 0.f);
        } else if (tid >= 512) {
            // stream part 1: m = 1..10 (pair-pipelined, depth-2)
            float4 pA0, pB0, pA1, pB1, qA0, qB0, qA1, qB1;
            SLOAD(1, pA0, pB0); SLOAD(2, pA1, pB1);
            #pragma unroll
            for (int m = 1; m <= 9; m += 2) {
                if (m + 2 <= 9) { SLOAD(m + 2, qA0, qB0); SLOAD(m + 3, qA1, qB1); }
                SCOMP(m, pA0, pB0);
                SCOMP(m + 1, pA1, pB1);
                pA0 = qA0; pB0 = qB0; pA1 = qA1; pB1 = qB1;
            }
        }
        __syncthreads();   // B2

        // ---- concurrent post-section ----
        if (tid >= 512) {
            // stream part 2: m = 11..19 (load for 19 issued early)
            float4 lA19, lB19; SLOAD(19, lA19, lB19);
            float4 pA0, pB0, pA1, pB1, qA0, qB0, qA1, qB1;
            SLOAD(11, pA0, pB0); SLOAD(12, pA1, pB1);
            #pragma unroll
            for (int m = 11; m <= 17; m += 2) {
                if (m + 2 <= 17) { SLOAD(m + 2, qA0, qB0); SLOAD(m + 3, qA1, qB1); }
                SCOMP(m, pA0, pB0);
                SCOMP(m + 1, pA1, pB1);
                pA0 = qA0; pB0 = qB0; pA1 = qA1; pB1 = qB1;
            }
            // m=10 (deferred from part1 boundary)... part1 covered 1..10? no:
            // part1 loop m=1,3,5,7,9 computed m..m+1 => 1..10 complete.
            SCOMP(19, lA19, lB19);
            // write partial(t+1), exclusively owned slots
            red[par ^ 1][sg][sj][0] = sa0;
            red[par ^ 1][sg][sj][1] = sa1;
            red[par ^ 1][sg][sj][2] = sa2;
            red[par ^ 1][sg][sj][3] = sa3;
        } else if (tid < 64) {
            // ---- tail (wave 0; intra-wave LDS ordering) ----
            const int j = tid;
            {   // ai: 64 lanes = 4b x 16i
                int bb = j >> 4, i = j & 15;
                const float4* epq = (const float4*)&e1S[bb][0];
                float s = b2_l[i];
                #pragma unroll
                for (int q = 0; q < 16; ++q) s += dot4(*(const float4*)&W2_l[i * 68 + q * 4], epq[q]);
                aiS[bb][i] = fmaxf(s, 0.f);
            }
            if (j < 32) {   // expert heads o: 4b x 8c
                int bb = j >> 3, c = j & 7;
                const float4* np = (const float4*)&nhS[bb][c][0];
                const float4* wp = (const float4*)&Wo_l[c][0];
                float s = bo_l[c];
                #pragma unroll
                for (int q4 = 0; q4 < 4; ++q4) s += dot4(np[q4], wp[q4]);
                oS[bb][c] = s;
            }
            #pragma unroll
            for (int l = 0; l < 2; ++l) {   // agent LSTM: 4b x 16h
                int bb = j >> 4, h = j & 15;
                const float4* ip = (l == 0) ? (const float4*)&aiS[bb][0]
                                            : (const float4*)&ahS[0][bb][0];
                const float4* hp = (const float4*)&ahS[l][bb][0];
                float4 i0 = ip[0], i1 = ip[1], i2 = ip[2], i3 = ip[3];
                float4 h0 = hp[0], h1 = hp[1], h2v = hp[2], h3 = hp[3];
                float zg[4];
                #pragma unroll
                for (int gi = 0; gi < 4; ++gi) {
                    int g = gi * 16 + h;
                    const float* wi = &WaI[l][g * 20];
                    const float* wh = &WaH[l][g * 20];
                    float z = ba_l[l][g];
                    z += dot4(i0, *(const float4*)&wi[0]) + dot4(i1, *(const float4*)&wi[4])
                       + dot4(i2, *(const float4*)&wi[8]) + dot4(i3, *(const float4*)&wi[12]);
                    z += dot4(h0, *(const float4*)&wh[0]) + dot4(h1, *(const float4*)&wh[4])
                       + dot4(h2v, *(const float4*)&wh[8]) + dot4(h3, *(const float4*)&wh[12]);
                    zg[gi] = z;
                }
                float c2 = sigm(zg[1]) * acS[l][bb][h] + sigm(zg[0]) * tanh_f(zg[2]);
                acS[l][bb][h] = c2;
                ahS[l][bb][h] = sigm(zg[3]) * tanh_f(c2);
            }
            if (j < 32) {   // gate logits + softmax + theta: 4b x 8c
                int bb = j >> 3, c = j & 7;
                const float4* hp = (const float4*)&ahS[1][bb][0];
                const float4* wg = (const float4*)&Wg_l[c][0];
                float s = bg_l[c];
                #pragma unroll
                for (int q = 0; q < 4; ++q) s += dot4(wg[q], hp[q]);
                glog[bb][c] = s;
                float4 ga = *(const float4*)&glog[bb][0];
                float4 gb = *(const float4*)&glog[bb][4];
                float mx = fmaxf(fmaxf(fmaxf(ga.x, ga.y), fmaxf(ga.z, ga.w)),
                                 fmaxf(fmaxf(gb.x, gb.y), fmaxf(gb.z, gb.w)));
                float sum = __expf(ga.x - mx) + __expf(ga.y - mx) + __expf(ga.z - mx) + __expf(ga.w - mx)
                          + __expf(gb.x - mx) + __expf(gb.y - mx) + __expf(gb.z - mx) + __expf(gb.w - mx);
                float p = __expf(s - mx) / sum;
                float th = 0.f;
                #pragma unroll
                for (int m = 0; m < 10; ++m) {
                    int sl = head + m; if (sl >= MEM) sl -= MEM;
                    th += fabsf(errS[bb][sl]);
                }
                th *= 0.25f;
                th = fminf(fmaxf(th, 0.f), 1.f);
                gateS[bb][c] = p * th + gateS[bb][c] * (1.f - th);
            }
            {   // combine: 4b x 16h
                int bb = j >> 4, h = j & 15;
                float se = 0.f, sc = 0.f;
                #pragma unroll
                for (int c = 0; c < 8; ++c) {
                    float g = gateS[bb][c];
                    se = fmaf(g, nhS[bb][c][h], se);
                    sc = fmaf(g, ncS[bb][c][h], sc);
                }
                ehS[bb][h] = se; ecS[bb][h] = sc;
            }
            if (j < NB) {   // pred + output
                float s = 0.f;
                #pragma unroll
                for (int c = 0; c < 8; ++c) s = fmaf(gateS[j][c], oS[j][c], s);
                predS[j] = s;
                out[(b0 + j) * S_LEN + t] = s;
            }
        }
        __syncthreads();   // B3
    }
}

extern "C" void kernel_launch(void* const* d_in, const int* in_sizes, int n_in,
                              void* d_out, int out_size, void* d_ws, size_t ws_size,
                              hipStream_t stream) {
    const float* xp    = (const float*)d_in[0];
    const float* pred0 = (const float*)d_in[1];
    const float* gate0 = (const float*)d_in[2];
    const float* W_ih  = (const float*)d_in[3];
    const float* W_hh  = (const float*)d_in[4];
    const float* b_ih  = (const float*)d_in[5];
    const float* b_hh  = (const float*)d_in[6];
    const float* W_o   = (const float*)d_in[7];
    const float* b_o   = (const float*)d_in[8];
    const float* W1    = (const float*)d_in[9];
    const float* b1    = (const float*)d_in[10];
    const float* W2    = (const float*)d_in[11];
    const float* b2    = (const float*)d_in[12];
    const float* Wg    = (const float*)d_in[13];
    const float* bg    = (const float*)d_in[14];
    const float* Wa_ih = (const float*)d_in[15];
    const float* Wa_hh = (const float*)d_in[16];
    const float* ba_ih = (const float*)d_in[17];
    const float* ba_hh = (const float*)d_in[18];
    _Float16* W1F = (_Float16*)d_ws;                 // 320 KB

    prep_w1<<<(MEM * KS * 64 * 8 + 255) / 256, 256, 0, stream>>>(W1, W1F);
    mmoe_kernel<<<512 / NB, NTHR, 0, stream>>>(
        xp, pred0, gate0, W_ih, W_hh, b_ih, b_hh, W_o, b_o,
        W1, b1, W2, b2, Wg, bg, Wa_ih, Wa_hh, ba_ih, ba_hh,
        W1F, (float*)d_out);
}

// Round 10
// 2170.616 us; speedup vs baseline: 1.3424x; 1.3424x over previous
//
#include <hip/hip_runtime.h>
#include <math.h>

#define S_LEN 256
#define NCELL 8
#define HID 16
#define MEM 20
#define NB 4
#define NTHR 1024
#define KS 16

typedef _Float16 h2 __attribute__((ext_vector_type(2)));

#if defined(__has_builtin)
#if __has_builtin(__builtin_amdgcn_fdot2)
#define HAVE_FDOT2 1
#endif
#endif

__device__ __forceinline__ float sigm(float v) { return 1.0f / (1.0f + __expf(-v)); }
__device__ __forceinline__ float tanh_f(float v) { return 1.0f - 2.0f / (__expf(2.0f * v) + 1.0f); }
__device__ __forceinline__ float dot4(float4 a, float4 b) {
    return fmaf(a.x, b.x, fmaf(a.y, b.y, fmaf(a.z, b.z, a.w * b.w)));
}
__device__ __forceinline__ h2 bch2(float f) { return __builtin_bit_cast(h2, f); }
__device__ __forceinline__ float dot2acc(h2 a, h2 w, float c) {
#ifdef HAVE_FDOT2
    return __builtin_amdgcn_fdot2(a, w, c, false);
#else
    return fmaf((float)a.x, (float)w.x, fmaf((float)a.y, (float)w.y, c));
#endif
}

// W1 f32 [64][2580] -> W1F f16 [m][ks][j][8] (h-cols only), coalesced reads.
__global__ __launch_bounds__(256)
void prep_w1(const float* __restrict__ W1, _Float16* __restrict__ W1F) {
    int d = blockIdx.x * 256 + threadIdx.x;
    if (d < MEM * KS * 64 * 8) {
        int e = d & 7, j = (d >> 3) & 63, ks = (d >> 9) & 15, m = d >> 13;
        W1F[d] = (_Float16)W1[j * 2580 + m * 129 + ks * 8 + e];
    }
}

// R9 failed on VGPR spill (64-reg budget at NTHR=1024; depth-2 prefetch = 32
// live regs blew it -> scratch thrashed L2 -> FETCH 180MB). R10 keeps R8's
// spill-safe depth-1 stream loop but overlaps the ENTIRE m=1..19 stream
// (waves 8-15, partial for step t+1) with wave 0's e1-assembly + serial tail
// (LDS-latency-bound => mostly stalled => co-issues with stream). m=0 term
// (needs row_t) is a short section 2a by stream waves -> red0. 3 barriers.

// one m-row of the stream: accumulate 16 k-cols (2 slices) x 4 batches
#define STREAM_M(SL, WA, WB) { \
    h2 w0 = bch2(WA.x), w1 = bch2(WA.y), w2 = bch2(WA.z), w3 = bch2(WA.w); \
    h2 w4 = bch2(WB.x), w5 = bch2(WB.y), w6 = bch2(WB.z), w7 = bch2(WB.w); \
    const _Float16* rb = &ringH[0][SL][sg * 16]; \
    { float4 aA = *(const float4*)rb, aB = *(const float4*)(rb + 8); \
      sa0 = dot2acc(bch2(aA.x), w0, sa0); sa0 = dot2acc(bch2(aA.y), w1, sa0); \
      sa0 = dot2acc(bch2(aA.z), w2, sa0); sa0 = dot2acc(bch2(aA.w), w3, sa0); \
      sa0 = dot2acc(bch2(aB.x), w4, sa0); sa0 = dot2acc(bch2(aB.y), w5, sa0); \
      sa0 = dot2acc(bch2(aB.z), w6, sa0); sa0 = dot2acc(bch2(aB.w), w7, sa0); } \
    { float4 aA = *(const float4*)(rb + 2560), aB = *(const float4*)(rb + 2568); \
      sa1 = dot2acc(bch2(aA.x), w0, sa1); sa1 = dot2acc(bch2(aA.y), w1, sa1); \
      sa1 = dot2acc(bch2(aA.z), w2, sa1); sa1 = dot2acc(bch2(aA.w), w3, sa1); \
      sa1 = dot2acc(bch2(aB.x), w4, sa1); sa1 = dot2acc(bch2(aB.y), w5, sa1); \
      sa1 = dot2acc(bch2(aB.z), w6, sa1); sa1 = dot2acc(bch2(aB.w), w7, sa1); } \
    { float4 aA = *(const float4*)(rb + 5120), aB = *(const float4*)(rb + 5128); \
      sa2 = dot2acc(bch2(aA.x), w0, sa2); sa2 = dot2acc(bch2(aA.y), w1, sa2); \
      sa2 = dot2acc(bch2(aA.z), w2, sa2); sa2 = dot2acc(bch2(aA.w), w3, sa2); \
      sa2 = dot2acc(bch2(aB.x), w4, sa2); sa2 = dot2acc(bch2(aB.y), w5, sa2); \
      sa2 = dot2acc(bch2(aB.z), w6, sa2); sa2 = dot2acc(bch2(aB.w), w7, sa2); } \
    { float4 aA = *(const float4*)(rb + 7680), aB = *(const float4*)(rb + 7688); \
      sa3 = dot2acc(bch2(aA.x), w0, sa3); sa3 = dot2acc(bch2(aA.y), w1, sa3); \
      sa3 = dot2acc(bch2(aA.z), w2, sa3); sa3 = dot2acc(bch2(aA.w), w3, sa3); \
      sa3 = dot2acc(bch2(aB.x), w4, sa3); sa3 = dot2acc(bch2(aB.y), w5, sa3); \
      sa3 = dot2acc(bch2(aB.z), w6, sa3); sa3 = dot2acc(bch2(aB.w), w7, sa3); } }

// wave-0 e1 partial (prev-step stream partial + bias + f32 error column)
#define E1P(BB, V) { \
    V = b1_l[sj] \
      + red[par][0][BB][sj] + red[par][1][BB][sj] + red[par][2][BB][sj] \
      + red[par][3][BB][sj] + red[par][4][BB][sj] + red[par][5][BB][sj] \
      + red[par][6][BB][sj] + red[par][7][BB][sj]; \
    int sl_ = head; \
    _Pragma("unroll") \
    for (int m_ = 0; m_ < MEM; ++m_) { \
        V = fmaf(Werr_l[m_ * 64 + sj], errS[BB][sl_], V); \
        ++sl_; if (sl_ >= MEM) sl_ = 0; } }

// wave-0 e1 finalize (+ m=0 term from red0, relu)
#define E1F(BB, V) { \
    V += red0[0][BB][sj] + red0[1][BB][sj] + red0[2][BB][sj] + red0[3][BB][sj] \
       + red0[4][BB][sj] + red0[5][BB][sj] + red0[6][BB][sj] + red0[7][BB][sj]; \
    e1S[BB][sj] = fmaxf(V, 0.f); }

__global__ __attribute__((amdgpu_flat_work_group_size(NTHR, NTHR)))
void mmoe_kernel(const float* __restrict__ x, const float* __restrict__ pred0,
                 const float* __restrict__ gate0,
                 const float* __restrict__ W_ih, const float* __restrict__ W_hh,
                 const float* __restrict__ b_ih, const float* __restrict__ b_hh,
                 const float* __restrict__ W_o, const float* __restrict__ b_o,
                 const float* __restrict__ W1, const float* __restrict__ b1,
                 const float* __restrict__ W2, const float* __restrict__ b2,
                 const float* __restrict__ Wg, const float* __restrict__ bg,
                 const float* __restrict__ Wa_ih, const float* __restrict__ Wa_hh,
                 const float* __restrict__ ba_ih, const float* __restrict__ ba_hh,
                 const _Float16* __restrict__ W1F,
                 float* __restrict__ out)
{
    __shared__ __align__(16) _Float16 ringH[NB][MEM][128];   // memory rows (h), f16
    __shared__ float errS[NB][MEM];                          // error column, f32
    __shared__ __align__(16) float Whh_l[512 * 20];
    __shared__ float Wih_l[512], bias_l[512];
    __shared__ __align__(16) float WaI[2][64 * 20], WaH[2][64 * 20];
    __shared__ float ba_l[2][64];
    __shared__ __align__(16) float W2_l[16 * 68];
    __shared__ float b2_l[16];
    __shared__ __align__(16) float Wg_l[8][16], Wo_l[8][16];
    __shared__ float bg_l[8], bo_l[8];
    __shared__ float Werr_l[MEM * 64];                       // W1 col-128, f32
    __shared__ float b1_l[64];
    __shared__ float xS[NB][S_LEN];
    __shared__ __align__(16) float ehS[NB][HID], ecS[NB][HID];
    __shared__ __align__(16) float nhS[NB][NCELL][HID], ncS[NB][NCELL][HID];
    __shared__ float oS[NB][NCELL], predS[NB], gateS[NB][NCELL];
    __shared__ __align__(16) float ahS[2][NB][HID], acS[2][NB][HID];
    __shared__ __align__(16) float e1S[NB][64], aiS[NB][HID];
    __shared__ __align__(16) float glog[NB][8];
    __shared__ float red[2][8][NB][64];                      // stream partials (parity dbuf)
    __shared__ float red0[8][NB][64];                        // m=0 term

    const int tid = threadIdx.x;
    const int b0 = blockIdx.x * NB;
    const int sj = tid & 63;
    const int wv = tid >> 6;
    const int sg = wv - 8;                                   // stream group (waves 8-15)

    // ---- one-time staging ----
    for (int i = tid; i < 512 * 16; i += NTHR) { int g = i >> 4, q = i & 15; Whh_l[g * 20 + q] = W_hh[i]; }
    for (int i = tid; i < 512; i += NTHR) { Wih_l[i] = W_ih[i]; bias_l[i] = b_ih[i] + b_hh[i]; }
    for (int i = tid; i < 2048; i += NTHR) {
        int l = i >> 10, r = i & 1023, g = r >> 4, q = r & 15;
        WaI[l][g * 20 + q] = Wa_ih[i]; WaH[l][g * 20 + q] = Wa_hh[i];
    }
    for (int i = tid; i < 128; i += NTHR) { int l = i >> 6, g = i & 63; ba_l[l][g] = ba_ih[i] + ba_hh[i]; }
    for (int i = tid; i < 1024; i += NTHR) { int r = i >> 6, q = i & 63; W2_l[r * 68 + q] = W2[i]; }
    for (int i = tid; i < 1280; i += NTHR) { int m = i >> 6, j = i & 63; Werr_l[i] = W1[j * 2580 + m * 129 + 128]; }
    if (tid < 64) b1_l[tid] = b1[tid];
    if (tid < 16) b2_l[tid] = b2[tid];
    if (tid < 128) { int c = tid >> 4, h = tid & 15; Wg_l[c][h] = Wg[tid]; Wo_l[c][h] = W_o[tid]; }
    if (tid < 8) { bg_l[tid] = bg[tid]; bo_l[tid] = b_o[tid]; }
    for (int i = tid; i < NB * S_LEN; i += NTHR) { int b = i >> 8, s = i & 255; xS[b][s] = x[(b0 + b) * S_LEN + s]; }
    for (int i = tid; i < NB * MEM * 128; i += NTHR) ((_Float16*)ringH)[i] = (_Float16)0.0f;
    for (int i = tid; i < 8 * NB * 64; i += NTHR) ((float*)red)[i] = 0.0f;  // red[0] = partial(t=0) = 0
    if (tid < NB * MEM) { int b = tid / MEM, m = tid % MEM; errS[b][m] = 0.5f; }
    if (tid < NB * HID) {
        int b = tid >> 4, h = tid & 15;
        ehS[b][h] = 0.f; ecS[b][h] = 0.f;
        ahS[0][b][h] = 0.f; ahS[1][b][h] = 0.f;
        acS[0][b][h] = 0.f; acS[1][b][h] = 0.f;
    }
    if (tid < NB) predS[tid] = pred0[b0 + tid];
    if (tid < NB * NCELL) { int b = tid >> 3, c = tid & 7; gateS[b][c] = gate0[(b0 + b) * NCELL + c]; }
    __syncthreads();

    const float4* W1F4 = (const float4*)W1F;
    const float4* wbase0 = W1F4 + (2 * sg) * 64 + sj;        // slice 2sg, m=0
    const float4* wbase1 = wbase0 + 64;                      // slice 2sg+1, m=0

    int head = 0;
    #pragma unroll 1
    for (int t = 0; t < S_LEN; ++t) {
        head = (head == 0) ? (MEM - 1) : (head - 1);
        const int par = t & 1, np = par ^ 1;
        float v0, v1, v2, v3;                                // wave-0 e1 partials
        float sa0, sa1, sa2, sa3;                            // stream accumulators

        // ---- Section 1: phase A (waves 0-7) ----
        if (tid < 512) {
            int b = tid >> 7, c = (tid >> 4) & 7, h = tid & 15;
            float xv = xS[b][t];
            const float4* ep = (const float4*)&ehS[b][0];
            float4 e0 = ep[0], e1v = ep[1], e2 = ep[2], e3 = ep[3];
            float zg[4];
            #pragma unroll
            for (int gi = 0; gi < 4; ++gi) {
                int g = c * 64 + gi * 16 + h;
                const float* wr = &Whh_l[g * 20];
                float z = bias_l[g] + xv * Wih_l[g];
                z += dot4(e0, *(const float4*)&wr[0]) + dot4(e1v, *(const float4*)&wr[4])
                   + dot4(e2, *(const float4*)&wr[8]) + dot4(e3, *(const float4*)&wr[12]);
                zg[gi] = z;
            }
            float cc = ecS[b][h];
            float c2 = sigm(zg[1]) * cc + sigm(zg[0]) * tanh_f(zg[2]);
            float hv = sigm(zg[3]) * tanh_f(c2);
            nhS[b][c][h] = hv; ncS[b][c][h] = c2;
            ringH[b][head][c * 16 + h] = (_Float16)hv;
            if (tid < NB) errS[tid][head] = xS[tid][t] - predS[tid];
        }
        __syncthreads();   // B1

        // ---- Section 2a (short): stream waves do m=0 term; wave 0 does e1 partials ----
        if (wv >= 8) {
            float4 wA = *wbase0, wB = *wbase1;
            sa0 = 0.f; sa1 = 0.f; sa2 = 0.f; sa3 = 0.f;
            STREAM_M(head, wA, wB);
            red0[sg][0][sj] = sa0; red0[sg][1][sj] = sa1;
            red0[sg][2][sj] = sa2; red0[sg][3][sj] = sa3;
        } else if (wv == 0) {
            E1P(0, v0) E1P(1, v1) E1P(2, v2) E1P(3, v3)
        }
        __syncthreads();   // B2

        // ---- Section 2b: stream m=1..19 (waves 8-15) || e1 finalize + tail (wave 0) ----
        if (wv >= 8) {
            sa0 = 0.f; sa1 = 0.f; sa2 = 0.f; sa3 = 0.f;
            const float4* wp0 = wbase0 + 1024;               // m=1 (stride 1024 float4 per m)
            const float4* wp1 = wbase1 + 1024;
            float4 pA = *wp0, pB = *wp1;
            int sl = head;                                   // m=1 -> slot head
            #pragma unroll 1
            for (int m = 1; m <= 19; ++m) {
                float4 wA = pA, wB = pB;
                wp0 += 1024; wp1 += 1024;
                if (m < 19) { pA = *wp0; pB = *wp1; }
                STREAM_M(sl, wA, wB);
                ++sl; if (sl >= MEM) sl = 0;
            }
            red[np][sg][0][sj] = sa0; red[np][sg][1][sj] = sa1;
            red[np][sg][2][sj] = sa2; red[np][sg][3][sj] = sa3;
        } else if (wv == 0) {
            E1F(0, v0) E1F(1, v1) E1F(2, v2) E1F(3, v3)
            const int j = sj;
            {   // ai: 64 lanes = 4b x 16i
                int bb = j >> 4, i = j & 15;
                const float4* epq = (const float4*)&e1S[bb][0];
                float s = b2_l[i];
                #pragma unroll
                for (int q = 0; q < 16; ++q) s += dot4(*(const float4*)&W2_l[i * 68 + q * 4], epq[q]);
                aiS[bb][i] = fmaxf(s, 0.f);
            }
            if (j < 32) {   // expert heads o: 4b x 8c
                int bb = j >> 3, c = j & 7;
                const float4* np_ = (const float4*)&nhS[bb][c][0];
                const float4* wp = (const float4*)&Wo_l[c][0];
                float s = bo_l[c];
                #pragma unroll
                for (int q4 = 0; q4 < 4; ++q4) s += dot4(np_[q4], wp[q4]);
                oS[bb][c] = s;
            }
            #pragma unroll
            for (int l = 0; l < 2; ++l) {   // agent LSTM: 4b x 16h
                int bb = j >> 4, h = j & 15;
                const float4* ip = (l == 0) ? (const float4*)&aiS[bb][0]
                                            : (const float4*)&ahS[0][bb][0];
                const float4* hp = (const float4*)&ahS[l][bb][0];
                float4 i0 = ip[0], i1 = ip[1], i2 = ip[2], i3 = ip[3];
                float4 h0 = hp[0], h1 = hp[1], h2v = hp[2], h3 = hp[3];
                float zg[4];
                #pragma unroll
                for (int gi = 0; gi < 4; ++gi) {
                    int g = gi * 16 + h;
                    const float* wi = &WaI[l][g * 20];
                    const float* wh = &WaH[l][g * 20];
                    float z = ba_l[l][g];
                    z += dot4(i0, *(const float4*)&wi[0]) + dot4(i1, *(const float4*)&wi[4])
                       + dot4(i2, *(const float4*)&wi[8]) + dot4(i3, *(const float4*)&wi[12]);
                    z += dot4(h0, *(const float4*)&wh[0]) + dot4(h1, *(const float4*)&wh[4])
                       + dot4(h2v, *(const float4*)&wh[8]) + dot4(h3, *(const float4*)&wh[12]);
                    zg[gi] = z;
                }
                float c2 = sigm(zg[1]) * acS[l][bb][h] + sigm(zg[0]) * tanh_f(zg[2]);
                acS[l][bb][h] = c2;
                ahS[l][bb][h] = sigm(zg[3]) * tanh_f(c2);
            }
            if (j < 32) {   // gate logits + softmax + theta: 4b x 8c
                int bb = j >> 3, c = j & 7;
                const float4* hp = (const float4*)&ahS[1][bb][0];
                const float4* wg = (const float4*)&Wg_l[c][0];
                float s = bg_l[c];
                #pragma unroll
                for (int q = 0; q < 4; ++q) s += dot4(wg[q], hp[q]);
                glog[bb][c] = s;
                float4 ga = *(const float4*)&glog[bb][0];
                float4 gb = *(const float4*)&glog[bb][4];
                float mx = fmaxf(fmaxf(fmaxf(ga.x, ga.y), fmaxf(ga.z, ga.w)),
                                 fmaxf(fmaxf(gb.x, gb.y), fmaxf(gb.z, gb.w)));
                float sum = __expf(ga.x - mx) + __expf(ga.y - mx) + __expf(ga.z - mx) + __expf(ga.w - mx)
                          + __expf(gb.x - mx) + __expf(gb.y - mx) + __expf(gb.z - mx) + __expf(gb.w - mx);
                float p = __expf(s - mx) / sum;
                float th = 0.f;
                #pragma unroll
                for (int m = 0; m < 10; ++m) {
                    int sl = head + m; if (sl >= MEM) sl -= MEM;
                    th += fabsf(errS[bb][sl]);
                }
                th *= 0.25f;
                th = fminf(fmaxf(th, 0.f), 1.f);
                gateS[bb][c] = p * th + gateS[bb][c] * (1.f - th);
            }
            {   // combine: 4b x 16h
                int bb = j >> 4, h = j & 15;
                float se = 0.f, sc = 0.f;
                #pragma unroll
                for (int c = 0; c < 8; ++c) {
                    float g = gateS[bb][c];
                    se = fmaf(g, nhS[bb][c][h], se);
                    sc = fmaf(g, ncS[bb][c][h], sc);
                }
                ehS[bb][h] = se; ecS[bb][h] = sc;
            }
            if (j < NB) {   // pred + output
                float s = 0.f;
                #pragma unroll
                for (int c = 0; c < 8; ++c) s = fmaf(gateS[j][c], oS[j][c], s);
                predS[j] = s;
                out[(b0 + j) * S_LEN + t] = s;
            }
        }
        __syncthreads();   // B3
    }
}

extern "C" void kernel_launch(void* const* d_in, const int* in_sizes, int n_in,
                              void* d_out, int out_size, void* d_ws, size_t ws_size,
                              hipStream_t stream) {
    const float* xp    = (const float*)d_in[0];
    const float* pred0 = (const float*)d_in[1];
    const float* gate0 = (const float*)d_in[2];
    const float* W_ih  = (const float*)d_in[3];
    const float* W_hh  = (const float*)d_in[4];
    const float* b_ih  = (const float*)d_in[5];
    const float* b_hh  = (const float*)d_in[6];
    const float* W_o   = (const float*)d_in[7];
    const float* b_o   = (const float*)d_in[8];
    const float* W1    = (const float*)d_in[9];
    const float* b1    = (const float*)d_in[10];
    const float* W2    = (const float*)d_in[11];
    const float* b2    = (const float*)d_in[12];
    const float* Wg    = (const float*)d_in[13];
    const float* bg    = (const float*)d_in[14];
    const float* Wa_ih = (const float*)d_in[15];
    const float* Wa_hh = (const float*)d_in[16];
    const float* ba_ih = (const float*)d_in[17];
    const float* ba_hh = (const float*)d_in[18];
    _Float16* W1F = (_Float16*)d_ws;                 // 320 KB

    prep_w1<<<(MEM * KS * 64 * 8 + 255) / 256, 256, 0, stream>>>(W1, W1F);
    mmoe_kernel<<<512 / NB, NTHR, 0, stream>>>(
        xp, pred0, gate0, W_ih, W_hh, b_ih, b_hh, W_o, b_o,
        W1, b1, W2, b2, Wg, bg, Wa_ih, Wa_hh, ba_ih, ba_hh,
        W1F, (float*)d_out);
}

// Round 11
// 1293.733 us; speedup vs baseline: 2.2522x; 1.6778x over previous
//
#include <hip/hip_runtime.h>
#include <math.h>

#define S_LEN 256
#define NCELL 8
#define HID 16
#define MEM 20
#define NB 4
#define NTHR 512

typedef _Float16 v8h __attribute__((ext_vector_type(8)));
typedef float v4f __attribute__((ext_vector_type(4)));

__device__ __forceinline__ float sigm(float v) { return 1.0f / (1.0f + __expf(-v)); }
__device__ __forceinline__ float tanh_f(float v) { return 1.0f - 2.0f / (__expf(2.0f * v) + 1.0f); }
__device__ __forceinline__ float dot4(float4 a, float4 b) {
    return fmaf(a.x, b.x, fmaf(a.y, b.y, fmaf(a.z, b.z, a.w * b.w)));
}
__device__ __forceinline__ v4f mfma16(v8h a, v8h b, v4f c) {
    return __builtin_amdgcn_mfma_f32_16x16x32_f16(a, b, c, 0, 0, 0);
}

// W1 f32 [64][2580] -> W1F f16 in MFMA A-fragment order.
// tile t = m*4+kc (k-tile of 32 within m-row h-part), jt = j-tile (0..3).
// A-frag: lane (mrow=lane&15, quad=lane>>4) holds A[j=jt*16+mrow][k=kc*32+quad*8+e].
__global__ __launch_bounds__(256)
void prep_w1(const float* __restrict__ W1, _Float16* __restrict__ W1F) {
    int idx = blockIdx.x * 256 + threadIdx.x;
    if (idx < MEM * 4 * 4 * 64 * 8) {                       // 163840
        int e = idx & 7;
        int lane = (idx >> 3) & 63;
        int jt = (idx >> 9) & 3;
        int t = idx >> 11;                                  // 0..79
        int m = t >> 2, kc = t & 3;
        int j = jt * 16 + (lane & 15);
        int k = kc * 32 + (lane >> 4) * 8 + e;
        W1F[idx] = (_Float16)W1[j * 2580 + m * 129 + k];
    }
}

// R10 post-mortem: stream bound by LDS INSTRUCTION ISSUE (1280 broadcast
// ds_read_b128/step/CU), not L2 or VALU. MFMA broadcasts B in hardware:
// per k-tile 1 ds_read + 4 coalesced A-loads + 4 mfma. N=16 carries the 4
// batches (cols 4-15 junk, ignored). NTHR=512 -> 128-VGPR budget, ~75 live,
// no spill. Pipeline skeleton unchanged: 2a m=0 + e1-partial, 2b m=1..19
// stream (waves 1-7) || tail (wave 0). 3 barriers/step.
#define E1P(BB, V) { \
    V = b1_l[lane] \
      + red[par][1][BB][lane] + red[par][2][BB][lane] + red[par][3][BB][lane] \
      + red[par][4][BB][lane] + red[par][5][BB][lane] + red[par][6][BB][lane] \
      + red[par][7][BB][lane]; \
    int sl_ = head; \
    _Pragma("unroll") \
    for (int m_ = 0; m_ < MEM; ++m_) { \
        V = fmaf(Werr_l[m_ * 64 + lane], errS[BB][sl_], V); \
        ++sl_; if (sl_ >= MEM) sl_ = 0; } }

#define E1F(BB, V) { \
    V += red0[0][BB][lane] + red0[1][BB][lane] + red0[2][BB][lane] + red0[3][BB][lane]; \
    e1S[BB][lane] = fmaxf(V, 0.f); }

__global__ __attribute__((amdgpu_flat_work_group_size(NTHR, NTHR)))
void mmoe_kernel(const float* __restrict__ x, const float* __restrict__ pred0,
                 const float* __restrict__ gate0,
                 const float* __restrict__ W_ih, const float* __restrict__ W_hh,
                 const float* __restrict__ b_ih, const float* __restrict__ b_hh,
                 const float* __restrict__ W_o, const float* __restrict__ b_o,
                 const float* __restrict__ W1, const float* __restrict__ b1,
                 const float* __restrict__ W2, const float* __restrict__ b2,
                 const float* __restrict__ Wg, const float* __restrict__ bg,
                 const float* __restrict__ Wa_ih, const float* __restrict__ Wa_hh,
                 const float* __restrict__ ba_ih, const float* __restrict__ ba_hh,
                 const _Float16* __restrict__ W1F,
                 float* __restrict__ out)
{
    __shared__ __align__(16) _Float16 ringH[NB][MEM][128];   // memory rows (h), f16
    __shared__ float errS[NB][MEM];                          // error column, f32
    __shared__ __align__(16) float Whh_l[512 * 20];
    __shared__ float Wih_l[512], bias_l[512];
    __shared__ __align__(16) float WaI[2][64 * 20], WaH[2][64 * 20];
    __shared__ float ba_l[2][64];
    __shared__ __align__(16) float W2_l[16 * 68];
    __shared__ float b2_l[16];
    __shared__ __align__(16) float Wg_l[8][16], Wo_l[8][16];
    __shared__ float bg_l[8], bo_l[8];
    __shared__ float Werr_l[MEM * 64];                       // W1 col-128, f32
    __shared__ float b1_l[64];
    __shared__ float xS[NB][S_LEN];
    __shared__ __align__(16) float ehS[NB][HID], ecS[NB][HID];
    __shared__ __align__(16) float nhS[NB][NCELL][HID], ncS[NB][NCELL][HID];
    __shared__ float oS[NB][NCELL], predS[NB], gateS[NB][NCELL];
    __shared__ __align__(16) float ahS[2][NB][HID], acS[2][NB][HID];
    __shared__ __align__(16) float e1S[NB][64], aiS[NB][HID];
    __shared__ __align__(16) float glog[NB][8];
    __shared__ __align__(16) float red[2][8][NB][64];        // stream partials (parity dbuf)
    __shared__ __align__(16) float red0[4][NB][64];          // m=0 term per kc

    const int tid = threadIdx.x;
    const int b0 = blockIdx.x * NB;
    const int lane = tid & 63, wv = tid >> 6;
    const int quad = lane >> 4, nn = lane & 15, bb4 = nn & 3;

    // ---- one-time staging ----
    for (int i = tid; i < 512 * 16; i += NTHR) { int g = i >> 4, q = i & 15; Whh_l[g * 20 + q] = W_hh[i]; }
    for (int i = tid; i < 512; i += NTHR) { Wih_l[i] = W_ih[i]; bias_l[i] = b_ih[i] + b_hh[i]; }
    for (int i = tid; i < 2048; i += NTHR) {
        int l = i >> 10, r = i & 1023, g = r >> 4, q = r & 15;
        WaI[l][g * 20 + q] = Wa_ih[i]; WaH[l][g * 20 + q] = Wa_hh[i];
    }
    for (int i = tid; i < 128; i += NTHR) { int l = i >> 6, g = i & 63; ba_l[l][g] = ba_ih[i] + ba_hh[i]; }
    for (int i = tid; i < 1024; i += NTHR) { int r = i >> 6, q = i & 63; W2_l[r * 68 + q] = W2[i]; }
    for (int i = tid; i < 1280; i += NTHR) { int m = i >> 6, j = i & 63; Werr_l[i] = W1[j * 2580 + m * 129 + 128]; }
    if (tid < 64) b1_l[tid] = b1[tid];
    if (tid < 16) b2_l[tid] = b2[tid];
    if (tid < 128) { int c = tid >> 4, h = tid & 15; Wg_l[c][h] = Wg[tid]; Wo_l[c][h] = W_o[tid]; }
    if (tid < 8) { bg_l[tid] = bg[tid]; bo_l[tid] = b_o[tid]; }
    for (int i = tid; i < NB * S_LEN; i += NTHR) { int b = i >> 8, s = i & 255; xS[b][s] = x[(b0 + b) * S_LEN + s]; }
    for (int i = tid; i < NB * MEM * 128; i += NTHR) ((_Float16*)ringH)[i] = (_Float16)0.0f;
    for (int i = tid; i < 2 * 8 * NB * 64; i += NTHR) ((float*)red)[i] = 0.0f;
    if (tid < NB * MEM) { int b = tid / MEM, m = tid % MEM; errS[b][m] = 0.5f; }
    if (tid < NB * HID) {
        int b = tid >> 4, h = tid & 15;
        ehS[b][h] = 0.f; ecS[b][h] = 0.f;
        ahS[0][b][h] = 0.f; ahS[1][b][h] = 0.f;
        acS[0][b][h] = 0.f; acS[1][b][h] = 0.f;
    }
    if (tid < NB) predS[tid] = pred0[b0 + tid];
    if (tid < NB * NCELL) { int b = tid >> 3, c = tid & 7; gateS[b][c] = gate0[(b0 + b) * NCELL + c]; }
    __syncthreads();

    const v8h* Wb = (const v8h*)W1F;

    int head = 0;
    #pragma unroll 1
    for (int t = 0; t < S_LEN; ++t) {
        head = (head == 0) ? (MEM - 1) : (head - 1);
        const int par = t & 1, np = par ^ 1;
        float v0, v1, v2, v3;                                // wave-0 e1 partials

        // ---- Section 1: phase A (all 512 threads) ----
        {
            int b = tid >> 7, c = (tid >> 4) & 7, h = tid & 15;
            float xv = xS[b][t];
            const float4* ep = (const float4*)&ehS[b][0];
            float4 e0 = ep[0], e1v = ep[1], e2 = ep[2], e3 = ep[3];
            float zg[4];
            #pragma unroll
            for (int gi = 0; gi < 4; ++gi) {
                int g = c * 64 + gi * 16 + h;
                const float* wr = &Whh_l[g * 20];
                float z = bias_l[g] + xv * Wih_l[g];
                z += dot4(e0, *(const float4*)&wr[0]) + dot4(e1v, *(const float4*)&wr[4])
                   + dot4(e2, *(const float4*)&wr[8]) + dot4(e3, *(const float4*)&wr[12]);
                zg[gi] = z;
            }
            float cc = ecS[b][h];
            float c2 = sigm(zg[1]) * cc + sigm(zg[0]) * tanh_f(zg[2]);
            float hv = sigm(zg[3]) * tanh_f(c2);
            nhS[b][c][h] = hv; ncS[b][c][h] = c2;
            ringH[b][head][c * 16 + h] = (_Float16)hv;
            if (tid < NB) errS[tid][head] = xS[tid][t] - predS[tid];
        }
        __syncthreads();   // B1

        // ---- Section 2a: m=0 term via MFMA (all 8 waves, 2 tiles each);
        //      wave 0 also assembles e1 partial (prev stream + err col) ----
        {
            int kc = wv >> 1, jt0 = (wv & 1) * 2;
            v8h bfrag = *(const v8h*)&ringH[bb4][head][kc * 32 + quad * 8];
            v8h a0 = Wb[(size_t)(kc * 4 + jt0) * 64 + lane];
            v8h a1 = Wb[(size_t)(kc * 4 + jt0 + 1) * 64 + lane];
            v4f c0 = {0.f, 0.f, 0.f, 0.f}, c1 = {0.f, 0.f, 0.f, 0.f};
            c0 = mfma16(a0, bfrag, c0);
            c1 = mfma16(a1, bfrag, c1);
            if (nn < 4) {
                *(v4f*)&red0[kc][nn][jt0 * 16 + quad * 4] = c0;
                *(v4f*)&red0[kc][nn][(jt0 + 1) * 16 + quad * 4] = c1;
            }
            if (wv == 0) { E1P(0, v0) E1P(1, v1) E1P(2, v2) E1P(3, v3) }
        }
        __syncthreads();   // B2

        // ---- Section 2b: stream m=1..19 (waves 1-7, MFMA) || tail (wave 0) ----
        if (wv >= 1) {
            int kt = (wv - 1) * 11;
            int ktEnd = kt + 11; if (ktEnd > 76) ktEnd = 76;
            v4f c0 = {0.f,0.f,0.f,0.f}, c1 = {0.f,0.f,0.f,0.f};
            v4f c2 = {0.f,0.f,0.f,0.f}, c3 = {0.f,0.f,0.f,0.f};
            size_t tb = (size_t)(4 + kt) * 256 + lane;
            v8h pA0 = Wb[tb], pA1 = Wb[tb + 64], pA2 = Wb[tb + 128], pA3 = Wb[tb + 192];
            int m0 = 1 + (kt >> 2), kc0 = kt & 3;
            int sl0 = head + m0 - 1; if (sl0 >= MEM) sl0 -= MEM;
            v8h pB = *(const v8h*)&ringH[bb4][sl0][kc0 * 32 + quad * 8];
            #pragma unroll 1
            for (; kt < ktEnd; ++kt) {
                v8h A0 = pA0, A1 = pA1, A2 = pA2, A3 = pA3, B = pB;
                int kn = kt + 1;
                if (kn < ktEnd) {
                    size_t tn = (size_t)(4 + kn) * 256 + lane;
                    pA0 = Wb[tn]; pA1 = Wb[tn + 64]; pA2 = Wb[tn + 128]; pA3 = Wb[tn + 192];
                    int mn = 1 + (kn >> 2), kcn = kn & 3;
                    int sn = head + mn - 1; if (sn >= MEM) sn -= MEM;
                    pB = *(const v8h*)&ringH[bb4][sn][kcn * 32 + quad * 8];
                }
                c0 = mfma16(A0, B, c0);
                c1 = mfma16(A1, B, c1);
                c2 = mfma16(A2, B, c2);
                c3 = mfma16(A3, B, c3);
            }
            if (nn < 4) {
                *(v4f*)&red[np][wv][nn][ 0 + quad * 4] = c0;
                *(v4f*)&red[np][wv][nn][16 + quad * 4] = c1;
                *(v4f*)&red[np][wv][nn][32 + quad * 4] = c2;
                *(v4f*)&red[np][wv][nn][48 + quad * 4] = c3;
            }
        } else {
            E1F(0, v0) E1F(1, v1) E1F(2, v2) E1F(3, v3)
            const int j = lane;
            {   // ai: 64 lanes = 4b x 16i
                int bb = j >> 4, i = j & 15;
                const float4* epq = (const float4*)&e1S[bb][0];
                float s = b2_l[i];
                #pragma unroll
                for (int q = 0; q < 16; ++q) s += dot4(*(const float4*)&W2_l[i * 68 + q * 4], epq[q]);
                aiS[bb][i] = fmaxf(s, 0.f);
            }
            if (j < 32) {   // expert heads o: 4b x 8c
                int bb = j >> 3, c = j & 7;
                const float4* np_ = (const float4*)&nhS[bb][c][0];
                const float4* wp = (const float4*)&Wo_l[c][0];
                float s = bo_l[c];
                #pragma unroll
                for (int q4 = 0; q4 < 4; ++q4) s += dot4(np_[q4], wp[q4]);
                oS[bb][c] = s;
            }
            #pragma unroll
            for (int l = 0; l < 2; ++l) {   // agent LSTM: 4b x 16h
                int bb = j >> 4, h = j & 15;
                const float4* ip = (l == 0) ? (const float4*)&aiS[bb][0]
                                            : (const float4*)&ahS[0][bb][0];
                const float4* hp = (const float4*)&ahS[l][bb][0];
                float4 i0 = ip[0], i1 = ip[1], i2 = ip[2], i3 = ip[3];
                float4 h0 = hp[0], h1 = hp[1], h2v = hp[2], h3 = hp[3];
                float zg[4];
                #pragma unroll
                for (int gi = 0; gi < 4; ++gi) {
                    int g = gi * 16 + h;
                    const float* wi = &WaI[l][g * 20];
                    const float* wh = &WaH[l][g * 20];
                    float z = ba_l[l][g];
                    z += dot4(i0, *(const float4*)&wi[0]) + dot4(i1, *(const float4*)&wi[4])
                       + dot4(i2, *(const float4*)&wi[8]) + dot4(i3, *(const float4*)&wi[12]);
                    z += dot4(h0, *(const float4*)&wh[0]) + dot4(h1, *(const float4*)&wh[4])
                       + dot4(h2v, *(const float4*)&wh[8]) + dot4(h3, *(const float4*)&wh[12]);
                    zg[gi] = z;
                }
                float c2 = sigm(zg[1]) * acS[l][bb][h] + sigm(zg[0]) * tanh_f(zg[2]);
                acS[l][bb][h] = c2;
                ahS[l][bb][h] = sigm(zg[3]) * tanh_f(c2);
            }
            if (j < 32) {   // gate logits + softmax + theta: 4b x 8c
                int bb = j >> 3, c = j & 7;
                const float4* hp = (const float4*)&ahS[1][bb][0];
                const float4* wg = (const float4*)&Wg_l[c][0];
                float s = bg_l[c];
                #pragma unroll
                for (int q = 0; q < 4; ++q) s += dot4(wg[q], hp[q]);
                glog[bb][c] = s;
                float4 ga = *(const float4*)&glog[bb][0];
                float4 gb = *(const float4*)&glog[bb][4];
                float mx = fmaxf(fmaxf(fmaxf(ga.x, ga.y), fmaxf(ga.z, ga.w)),
                                 fmaxf(fmaxf(gb.x, gb.y), fmaxf(gb.z, gb.w)));
                float sum = __expf(ga.x - mx) + __expf(ga.y - mx) + __expf(ga.z - mx) + __expf(ga.w - mx)
                          + __expf(gb.x - mx) + __expf(gb.y - mx) + __expf(gb.z - mx) + __expf(gb.w - mx);
                float p = __expf(s - mx) / sum;
                float th = 0.f;
                #pragma unroll
                for (int m = 0; m < 10; ++m) {
                    int sl = head + m; if (sl >= MEM) sl -= MEM;
                    th += fabsf(errS[bb][sl]);
                }
                th *= 0.25f;
                th = fminf(fmaxf(th, 0.f), 1.f);
                gateS[bb][c] = p * th + gateS[bb][c] * (1.f - th);
            }
            {   // combine: 4b x 16h
                int bb = j >> 4, h = j & 15;
                float se = 0.f, sc = 0.f;
                #pragma unroll
                for (int c = 0; c < 8; ++c) {
                    float g = gateS[bb][c];
                    se = fmaf(g, nhS[bb][c][h], se);
                    sc = fmaf(g, ncS[bb][c][h], sc);
                }
                ehS[bb][h] = se; ecS[bb][h] = sc;
            }
            if (j < NB) {   // pred + output
                float s = 0.f;
                #pragma unroll
                for (int c = 0; c < 8; ++c) s = fmaf(gateS[j][c], oS[j][c], s);
                predS[j] = s;
                out[(b0 + j) * S_LEN + t] = s;
            }
        }
        __syncthreads();   // B3
    }
}

extern "C" void kernel_launch(void* const* d_in, const int* in_sizes, int n_in,
                              void* d_out, int out_size, void* d_ws, size_t ws_size,
                              hipStream_t stream) {
    const float* xp    = (const float*)d_in[0];
    const float* pred0 = (const float*)d_in[1];
    const float* gate0 = (const float*)d_in[2];
    const float* W_ih  = (const float*)d_in[3];
    const float* W_hh  = (const float*)d_in[4];
    const float* b_ih  = (const float*)d_in[5];
    const float* b_hh  = (const float*)d_in[6];
    const float* W_o   = (const float*)d_in[7];
    const float* b_o   = (const float*)d_in[8];
    const float* W1    = (const float*)d_in[9];
    const float* b1    = (const float*)d_in[10];
    const float* W2    = (const float*)d_in[11];
    const float* b2    = (const float*)d_in[12];
    const float* Wg    = (const float*)d_in[13];
    const float* bg    = (const float*)d_in[14];
    const float* Wa_ih = (const float*)d_in[15];
    const float* Wa_hh = (const float*)d_in[16];
    const float* ba_ih = (const float*)d_in[17];
    const float* ba_hh = (const float*)d_in[18];
    _Float16* W1F = (_Float16*)d_ws;                 // 320 KB, MFMA A-frag order

    prep_w1<<<(MEM * 4 * 4 * 64 * 8 + 255) / 256, 256, 0, stream>>>(W1, W1F);
    mmoe_kernel<<<512 / NB, NTHR, 0, stream>>>(
        xp, pred0, gate0, W_ih, W_hh, b_ih, b_hh, W_o, b_o,
        W1, b1, W2, b2, Wg, bg, Wa_ih, Wa_hh, ba_ih, ba_hh,
        W1F, (float*)d_out);
}